// Round 2
// baseline (385.197 us; speedup 1.0000x reference)
//
#include <hip/hip_runtime.h>

// Link_Embedding: out[e] = concat(X[src[e]], X[dst[e]])
// X: 100000 x 128 fp32 (51.2 MB), idx: 320000 x 2 int32, out: 320000 x 256 fp32 (327.7 MB).
//
// R5 = R4 resubmitted verbatim (two GPU-acquisition timeouts in a row; the
// restructure below has never been measured -- keep the A/B vs 380 us clean).
//
// R4 theory: at 380 us we are 3.7x above the all-HBM roofline (~104 us) ->
// latency/issue-bound, not BW-bound. Two fixes:
//  1. idx values are wave-uniform per edge; move them to the SCALAR pipe.
//     Remap edges so each wave owns 8 CONSECUTIVE edges -> one uniform 64 B
//     idx block -> s_load_dwordx16 (lgkmcnt), off the vmcnt critical path.
//  2. MLP 4 -> 8 independent random 1 KB wave-gathers in flight per wave.
// Keep nontemporal stores (keep the 327 MB write stream out of L3 so the
// random row re-reads stay L3-resident).
//
// Mapping: wave w of block b handles edges e = b*32 + w*8 + k, k=0..7.
// Lanes 0-31 read the src row (32 x float4 = 512 B), lanes 32-63 the dst row.
// Store: out[e*64 + lane] -> contiguous 1 KB per (wave,k), fully coalesced.

typedef float f4 __attribute__((ext_vector_type(4)));

#define N_EDGES 320000
#define F4_PER_ROW 32          // float4 per input row (128 floats)
#define BLOCK 256
#define UNROLL 8
#define WAVES_PER_BLOCK 4      // BLOCK/64
#define EDGES_PER_BLOCK 32     // WAVES_PER_BLOCK * UNROLL
#define GRID 10000             // N_EDGES / EDGES_PER_BLOCK (exact, no tail)

__global__ __launch_bounds__(BLOCK) void link_embed_gather(
    const f4* __restrict__ X,    // N_NODES x 32 f4
    const int* __restrict__ idx, // N_EDGES x 2 (src, dst interleaved)
    f4*       __restrict__ out)  // N_EDGES x 64 f4
{
    const int lane = threadIdx.x & 63;
    // Force wave id into an SGPR so everything derived from it is provably
    // wave-uniform -> scalar loads for idx, scalar store-base math.
    const int wave = __builtin_amdgcn_readfirstlane((int)(threadIdx.x >> 6));

    const int ebase = blockIdx.x * EDGES_PER_BLOCK + wave * UNROLL;

    // Stage 1: idx for 8 consecutive edges = 64 B at a uniform address.
    // Expect s_load_dwordx16 on the scalar pipe (lgkmcnt, not vmcnt).
    int2 p[UNROLL];
    const int2* __restrict__ ip = (const int2*)idx + ebase;
    #pragma unroll
    for (int k = 0; k < UNROLL; ++k) {
        p[k] = ip[k];
    }

    const int which = lane >> 5;   // 0 -> src row, 1 -> dst row
    const int col   = lane & 31;   // f4 column within the row

    // Stage 2: 8 independent random row-gathers in flight (1 KB per wave-load:
    // two 512 B contiguous segments).
    f4 v[UNROLL];
    #pragma unroll
    for (int k = 0; k < UNROLL; ++k) {
        const int row = which ? p[k].y : p[k].x;
        v[k] = X[(long long)row * F4_PER_ROW + col];
    }

    // Stage 3: nontemporal streaming stores, SGPR base + lane offset,
    // contiguous 1 KB per (wave,k).
    f4* __restrict__ ob = out + (long long)ebase * 64 + lane;
    #pragma unroll
    for (int k = 0; k < UNROLL; ++k) {
        __builtin_nontemporal_store(v[k], ob + (long long)k * 64);
    }
}

extern "C" void kernel_launch(void* const* d_in, const int* in_sizes, int n_in,
                              void* d_out, int out_size, void* d_ws, size_t ws_size,
                              hipStream_t stream) {
    const f4*  X   = (const f4*)d_in[0];
    const int* idx = (const int*)d_in[1];
    f4*        out = (f4*)d_out;

    link_embed_gather<<<GRID, BLOCK, 0, stream>>>(X, idx, out);
}